// Round 10
// baseline (645.478 us; speedup 1.0000x reference)
//
#include <hip/hip_runtime.h>
#include <hip/hip_bf16.h>

#define N_NODES 100000
#define N_EDGES 1600000
#define F_IN 128
#define HID 64
#define SCAN_NB 98  // ceil(100000/1024)

typedef __attribute__((ext_vector_type(8))) short short8;

__device__ __forceinline__ float bfbits2f(unsigned short u) {
    union { unsigned int i; float f; } v;
    v.i = ((unsigned int)u) << 16;
    return v.f;
}
__device__ __forceinline__ unsigned short f2bfbits(float f) {
    union { float f; unsigned int i; } v;
    v.f = f;
    unsigned int r = v.i + 0x7FFFu + ((v.i >> 16) & 1u);  // RNE
    return (unsigned short)(r >> 16);
}
__device__ __forceinline__ unsigned int pack2bf(float a, float b) {
    return ((unsigned int)f2bfbits(b) << 16) | (unsigned int)f2bfbits(a);
}
__device__ __forceinline__ float lo_bf(unsigned int w) { return bfbits2f((unsigned short)(w & 0xFFFF)); }
__device__ __forceinline__ float hi_bf(unsigned int w) { return bfbits2f((unsigned short)(w >> 16)); }

// ---- detect flags AND zero deg (memset folded in); block 0 does flag logic ----
// flag[0] = edge_index is int64; flag[1] = model dtype is bf16
__global__ void k_detect(const int* __restrict__ ei, const unsigned int* __restrict__ x32,
                         int* __restrict__ flag, int* __restrict__ deg) {
    int gid = blockIdx.x * 1024 + threadIdx.x;
    if (gid < N_NODES) deg[gid] = 0;
    if (blockIdx.x != 0) return;
    __shared__ int s_odd, s_cnt;
    if (threadIdx.x == 0) { s_odd = 0; s_cnt = 0; }
    __syncthreads();
    int t = threadIdx.x;  // 1024 threads
    if (ei[2 * t + 1] != 0) atomicOr(&s_odd, 1);
    if (t < 256) {
        unsigned int u = x32[t];
        unsigned int e = (u >> 7) & 0xFF;
        if (e >= 0x68 && e <= 0x97) atomicAdd(&s_cnt, 1);
    }
    __syncthreads();
    if (t == 0) {
        flag[0] = (s_odd == 0) ? 1 : 0;
        flag[1] = (s_cnt >= 160) ? 1 : 0;
    }
}

__device__ __forceinline__ int clampN(int v) {
    v = v < 0 ? 0 : v;
    return v > (N_NODES - 1) ? (N_NODES - 1) : v;
}
__device__ __forceinline__ int load_row(const int* __restrict__ ei, int f, int e) {
    return clampN(f ? ei[2 * e] : ei[e]);
}
__device__ __forceinline__ int load_col(const int* __restrict__ ei, int f, int e) {
    return clampN(f ? ei[2 * (N_EDGES + e)] : ei[N_EDGES + e]);
}

// ---- fp32 weight scratch layout (floats) ----
#define WF_W1   0
#define WF_W2   8192
#define WF_L1W  12288
#define WF_B1   20480
#define WF_B2   20544
#define WF_L1B  20608
#define WF_L2W  20672
#define WF_L2B  20800
#define WF_TOT  20802

__global__ void k_prep(const void* W1, const void* W2, const void* L1W,
                       const void* b1, const void* b2, const void* L1b,
                       const void* L2W, const void* L2b,
                       const int* __restrict__ flag, float* __restrict__ Wf) {
    int idx = blockIdx.x * blockDim.x + threadIdx.x;
    if (idx >= WF_TOT) return;
    int bf = flag[1];
    const void* src; int k;
    if      (idx < WF_W2)  { src = W1;  k = idx; }
    else if (idx < WF_L1W) { src = W2;  k = idx - WF_W2; }
    else if (idx < WF_B1)  { src = L1W; k = idx - WF_L1W; }
    else if (idx < WF_B2)  { src = b1;  k = idx - WF_B1; }
    else if (idx < WF_L1B) { src = b2;  k = idx - WF_B2; }
    else if (idx < WF_L2W) { src = L1b; k = idx - WF_L1B; }
    else if (idx < WF_L2B) { src = L2W; k = idx - WF_L2W; }
    else                   { src = L2b; k = idx - WF_L2B; }
    Wf[idx] = bf ? bfbits2f(((const unsigned short*)src)[k]) : ((const float*)src)[k];
}

__global__ void k_deg(const int* __restrict__ ei, const int* __restrict__ flag,
                      int* __restrict__ deg) {
    int e = blockIdx.x * blockDim.x + threadIdx.x;
    if (e >= N_EDGES) return;
    atomicAdd(&deg[load_col(ei, flag[0], e)], 1);
}

// ---- CSR build: scan1 also computes dinv and zeroes deg (cursor reuse) ----
__global__ void k_scan1(int* __restrict__ deg, int* __restrict__ rowptr,
                        int* __restrict__ bsum, float* __restrict__ dinv) {
    __shared__ int s[1024];
    int t = threadIdx.x, b = blockIdx.x;
    int i = b * 1024 + t;
    int v = (i < N_NODES) ? deg[i] : 0;
    if (i < N_NODES) {
        dinv[i] = rsqrtf((float)(v + 1));
        deg[i] = 0;  // becomes the fill cursor
    }
    s[t] = v; __syncthreads();
    for (int off = 1; off < 1024; off <<= 1) {
        int add = (t >= off) ? s[t - off] : 0;
        __syncthreads();
        s[t] += add;
        __syncthreads();
    }
    if (i < N_NODES) rowptr[i] = s[t] - v;
    if (t == 1023) bsum[b] = s[t];
}

__global__ void k_scan2(const int* __restrict__ bsum, int* __restrict__ boff,
                        int* __restrict__ rowptr) {
    __shared__ int s[128];
    int t = threadIdx.x;
    int v = (t < SCAN_NB) ? bsum[t] : 0;
    s[t] = v; __syncthreads();
    for (int off = 1; off < 128; off <<= 1) {
        int add = (t >= off) ? s[t - off] : 0;
        __syncthreads();
        s[t] += add;
        __syncthreads();
    }
    if (t < SCAN_NB) boff[t] = s[t] - v;
    if (t == 0) rowptr[N_NODES] = N_EDGES;
}

__global__ void k_scan3(int* __restrict__ rowptr, const int* __restrict__ boff) {
    int t = threadIdx.x, b = blockIdx.x;
    int i = b * 1024 + t;
    if (i < N_NODES) rowptr[i] += boff[b];
}

// ---- fill: TWO 4-B scattered stores per edge (src,eid); 2 edges/thread for ILP ----
__global__ void k_fill(const int* __restrict__ ei, const int* __restrict__ flag,
                       const int* __restrict__ rowptr, int* __restrict__ cursor,
                       int* __restrict__ csr_src, int* __restrict__ csr_eid) {
    int e0 = (blockIdx.x * blockDim.x + threadIdx.x) * 2;
    if (e0 >= N_EDGES) return;
    int f = flag[0];
    int r0 = load_row(ei, f, e0), c0 = load_col(ei, f, e0);
    int r1 = load_row(ei, f, e0 + 1), c1 = load_col(ei, f, e0 + 1);
    int p0 = atomicAdd(&cursor[c0], 1);
    int p1 = atomicAdd(&cursor[c1], 1);
    int s0 = rowptr[c0] + p0;
    int s1 = rowptr[c1] + p1;
    csr_src[s0] = r0;
    csr_eid[s0] = e0;
    csr_src[s1] = r1;
    csr_eid[s1] = e0 + 1;
}

// ---- expand col per slot (sequential runs, no scatter) ----
__global__ void k_expand(const int* __restrict__ rowptr, int* __restrict__ csr_col) {
    int i = blockIdx.x * blockDim.x + threadIdx.x;
    if (i >= N_NODES) return;
    int k0 = rowptr[i], k1 = rowptr[i + 1];
    for (int k = k0; k < k1; k++) csr_col[k] = i;
}

// ===== node tables: packed bf16 rows, 32 u32 (=64 ch) per node =====
// All GEMMs: thread-per-node, 64 fp32 accs, WAVE-UNIFORM weight rows (s_load path).
// NEVER role-fuse these with latency-bound kernels (round-8: VGPR spill at 56).

__device__ __forceinline__ void st_row_bf(unsigned int* tab, int node, const float* acc, float s) {
    unsigned int* op = tab + (size_t)node * 32;
#pragma unroll
    for (int j = 0; j < 64; j += 2) op[j >> 1] = pack2bf(acc[j] * s, acc[j + 1] * s);
}

__device__ __forceinline__ void fma8(const float* xv, const float* __restrict__ Wf,
                                     int k0, float* acc) {
#pragma unroll
    for (int t = 0; t < 8; t++) {
        const float* wr = Wf + (k0 + t) * 64;
#pragma unroll
        for (int j = 0; j < 64; j++) acc[j] = fmaf(xv[t], wr[j], acc[j]);
    }
}

// ---- layer-1 GEMM: x [N,128] (bf16 or fp32) @ Wf[128,64] -> hs (bf16 rows) ----
__global__ void __launch_bounds__(256) k_gemm_in(const void* __restrict__ x,
                                                 const float* __restrict__ Wf,
                                                 const float* __restrict__ dinv,
                                                 unsigned int* __restrict__ hs,
                                                 const int* __restrict__ flag) {
    int i = blockIdx.x * blockDim.x + threadIdx.x;
    if (i >= N_NODES) return;
    int bf = flag[1];
    float acc[64];
#pragma unroll
    for (int j = 0; j < 64; j++) acc[j] = 0.f;
    if (bf) {
        const unsigned short* xp = (const unsigned short*)x + (size_t)i * F_IN;
#pragma unroll 2
        for (int k0 = 0; k0 < F_IN; k0 += 8) {
            short8 raw = *(const short8*)(xp + k0);
            float xv[8];
#pragma unroll
            for (int t = 0; t < 8; t++) xv[t] = bfbits2f((unsigned short)raw[t]);
            fma8(xv, Wf, k0, acc);
        }
    } else {
        const float* xp = (const float*)x + (size_t)i * F_IN;
#pragma unroll 2
        for (int k0 = 0; k0 < F_IN; k0 += 8) {
            float4 a = *(const float4*)(xp + k0);
            float4 b = *(const float4*)(xp + k0 + 4);
            float xv[8] = {a.x, a.y, a.z, a.w, b.x, b.y, b.z, b.w};
            fma8(xv, Wf, k0, acc);
        }
    }
    st_row_bf(hs, i, acc, dinv[i]);
}

// ---- generic K=64 GEMM: in (bf16 rows) @ W[64][64] -> out (bf16 rows); scale opt ----
__global__ void __launch_bounds__(256) k_gemm64(const unsigned int* __restrict__ in,
                                                const float* __restrict__ W,
                                                const float* __restrict__ scale,
                                                unsigned int* __restrict__ out) {
    int i = blockIdx.x * blockDim.x + threadIdx.x;
    if (i >= N_NODES) return;
    float acc[64];
#pragma unroll
    for (int j = 0; j < 64; j++) acc[j] = 0.f;
    const unsigned short* hp = (const unsigned short*)(in + (size_t)i * 32);
#pragma unroll 2
    for (int k0 = 0; k0 < 64; k0 += 8) {
        short8 raw = *(const short8*)(hp + k0);
        float xv[8];
#pragma unroll
        for (int t = 0; t < 8; t++) xv[t] = bfbits2f((unsigned short)raw[t]);
        fma8(xv, W, k0, acc);
    }
    float s = scale ? scale[i] : 1.f;
    st_row_bf(out, i, acc, s);
}

// ---- P1 then P2 sequentially per thread (64 accs live at a time -> no spill) ----
__global__ void __launch_bounds__(256) k_pair(unsigned int* __restrict__ h,
                                              const float* __restrict__ W,  // L1W [128][64]
                                              unsigned int* __restrict__ P1) {
    int i = blockIdx.x * blockDim.x + threadIdx.x;
    if (i >= N_NODES) return;
    const unsigned short* hp = (const unsigned short*)(h + (size_t)i * 32);
    float acc[64];
    // P1 = h @ W[0:64]
#pragma unroll
    for (int j = 0; j < 64; j++) acc[j] = 0.f;
#pragma unroll 2
    for (int k0 = 0; k0 < 64; k0 += 8) {
        short8 raw = *(const short8*)(hp + k0);
        float xv[8];
#pragma unroll
        for (int t = 0; t < 8; t++) xv[t] = bfbits2f((unsigned short)raw[t]);
        fma8(xv, W, k0, acc);
    }
    st_row_bf(P1, i, acc, 1.f);
    // P2 = h @ W[64:128], in place on h (row re-read is L1-hot)
#pragma unroll
    for (int j = 0; j < 64; j++) acc[j] = 0.f;
#pragma unroll 2
    for (int k0 = 0; k0 < 64; k0 += 8) {
        short8 raw = *(const short8*)(hp + k0);
        float xv[8];
#pragma unroll
        for (int t = 0; t < 8; t++) xv[t] = bfbits2f((unsigned short)raw[t]);
        fma8(xv, W + 64 * 64, k0, acc);
    }
    st_row_bf(h, i, acc, 1.f);
}

// ---- fused aggregate: wave = 2 nodes; 32 lanes/node; lane w handles ch 2w,2w+1 ----
// Neighbor loop unrolled x4: 4 outstanding gathers to hide L2/HBM load latency.
__global__ void __launch_bounds__(256) k_agg(const unsigned int* __restrict__ hs,
                                             const int* __restrict__ rowptr,
                                             const int* __restrict__ csr_src,
                                             const float* __restrict__ dinv,
                                             const float* __restrict__ bias,
                                             unsigned int* __restrict__ h) {
    int waves_per_blk = blockDim.x >> 6;
    int wid = blockIdx.x * waves_per_blk + (threadIdx.x >> 6);
    int lane = threadIdx.x & 63;
    int half = lane >> 5;
    int w = lane & 31;
    int node = wid * 2 + half;
    if (node >= N_NODES) return;
    unsigned int sw = hs[(size_t)node * 32 + w];
    float a0 = lo_bf(sw), a1 = hi_bf(sw);
    int k = rowptr[node], k1 = rowptr[node + 1];
    for (; k + 3 < k1; k += 4) {
        int s0 = csr_src[k], s1 = csr_src[k + 1], s2 = csr_src[k + 2], s3 = csr_src[k + 3];
        unsigned int w0 = hs[(size_t)s0 * 32 + w];
        unsigned int w1 = hs[(size_t)s1 * 32 + w];
        unsigned int w2 = hs[(size_t)s2 * 32 + w];
        unsigned int w3 = hs[(size_t)s3 * 32 + w];
        a0 += (lo_bf(w0) + lo_bf(w1)) + (lo_bf(w2) + lo_bf(w3));
        a1 += (hi_bf(w0) + hi_bf(w1)) + (hi_bf(w2) + hi_bf(w3));
    }
    for (; k < k1; k++) {
        unsigned int w0 = hs[(size_t)csr_src[k] * 32 + w];
        a0 += lo_bf(w0);
        a1 += hi_bf(w0);
    }
    float di = dinv[node];
    float v0 = fmaxf(fmaf(a0, di, bias[2 * w]), 0.f);
    float v1 = fmaxf(fmaf(a1, di, bias[2 * w + 1]), 0.f);
    h[(size_t)node * 32 + w] = pack2bf(v0, v1);
}

// ---- edge MLP in CSR order ----
__global__ void k_edge(const int* __restrict__ csr_src, const int* __restrict__ csr_eid,
                       const int* __restrict__ csr_col,
                       const unsigned int* __restrict__ P1, const unsigned int* __restrict__ P2,
                       const float* __restrict__ Wf, const int* __restrict__ flag,
                       void* __restrict__ out) {
    int s = blockIdx.x * blockDim.x + threadIdx.x;
    if (s >= N_EDGES) return;
    int r = csr_src[s], eid = csr_eid[s], c = csr_col[s];
    const float* l1b = Wf + WF_L1B;
    const float* l2w = Wf + WF_L2W;
    const float* l2b = Wf + WF_L2B;
    const uint4* p1 = (const uint4*)(P1 + (size_t)r * 32);
    const uint4* p2 = (const uint4*)(P2 + (size_t)c * 32);
    float s0 = 0.f, s1 = 0.f;
#pragma unroll
    for (int q = 0; q < 8; q++) {
        uint4 ua = p1[q];
        uint4 ub = p2[q];
        unsigned int wa[4] = {ua.x, ua.y, ua.z, ua.w};
        unsigned int wb[4] = {ub.x, ub.y, ub.z, ub.w};
#pragma unroll
        for (int t = 0; t < 4; t++) {
            int j = q * 8 + t * 2;
            float z;
            z = fmaxf(lo_bf(wa[t]) + lo_bf(wb[t]) + l1b[j + 0], 0.f);
            s0 = fmaf(z, l2w[(j + 0) * 2], s0); s1 = fmaf(z, l2w[(j + 0) * 2 + 1], s1);
            z = fmaxf(hi_bf(wa[t]) + hi_bf(wb[t]) + l1b[j + 1], 0.f);
            s0 = fmaf(z, l2w[(j + 1) * 2], s0); s1 = fmaf(z, l2w[(j + 1) * 2 + 1], s1);
        }
    }
    float z0 = s0 + l2b[0];
    float z1 = s1 + l2b[1];
    float m = fmaxf(z0, z1);
    float lse = m + __logf(__expf(z0 - m) + __expf(z1 - m));
    if (flag[1]) {
        ((unsigned int*)out)[eid] = pack2bf(z0 - lse, z1 - lse);
    } else {
        float2 v; v.x = z0 - lse; v.y = z1 - lse;
        ((float2*)out)[eid] = v;
    }
}

extern "C" void kernel_launch(void* const* d_in, const int* in_sizes, int n_in,
                              void* d_out, int out_size, void* d_ws, size_t ws_size,
                              hipStream_t stream) {
    const void* x   = d_in[0];
    const int*  ei  = (const int*)d_in[1];

    char* ws = (char*)d_ws;
    constexpr size_t KB = 1024;

    // peak use 46100 KB (same as rounds 6-9, which passed)
    int*   deg    = (int*)(ws);                    // 400 KB (reused as cursor)
    float* dinv   = (float*)(ws + 400 * KB);       // 400 KB
    int*   rowptr = (int*)(ws + 800 * KB);         // 400 KB + 4
    int*   flag   = (int*)(ws + 1204 * KB);        // 8 B
    int*   bsum   = (int*)(ws + 1208 * KB);        // 392 B
    int*   boff   = (int*)(ws + 1212 * KB);        // 392 B
    float* Wf     = (float*)(ws + 1216 * KB);      // 83.2 KB -> ends 1299.2 KB
    int*   csrsrc = (int*)(ws + 1300 * KB);        // 6400 KB -> ends 7700
    int*   csreid = (int*)(ws + 7700 * KB);        // 6400 KB -> ends 14100
    int*   csrcol = (int*)(ws + 14100 * KB);       // 6400 KB -> ends 20500
    unsigned int* hs = (unsigned int*)(ws + 20500 * KB);  // 12800 KB (later P1)
    unsigned int* h  = (unsigned int*)(ws + 33300 * KB);  // 12800 KB (later P2)

    // detect + deg-zero fused
    k_detect<<<SCAN_NB, 1024, 0, stream>>>(ei, (const unsigned int*)x, flag, deg);
    k_prep<<<(WF_TOT + 255) / 256, 256, 0, stream>>>(d_in[2], d_in[4], d_in[6], d_in[3],
                                                     d_in[5], d_in[7], d_in[8], d_in[9],
                                                     flag, Wf);
    k_deg<<<(N_EDGES + 255) / 256, 256, 0, stream>>>(ei, flag, deg);

    // CSR build (scan1 also emits dinv and zeroes deg -> cursor)
    k_scan1<<<SCAN_NB, 1024, 0, stream>>>(deg, rowptr, bsum, dinv);
    k_scan2<<<1, 128, 0, stream>>>(bsum, boff, rowptr);
    k_scan3<<<SCAN_NB, 1024, 0, stream>>>(rowptr, boff);
    k_fill<<<(N_EDGES / 2 + 255) / 256, 256, 0, stream>>>(ei, flag, rowptr, deg,
                                                          csrsrc, csreid);
    k_expand<<<(N_NODES + 255) / 256, 256, 0, stream>>>(rowptr, csrcol);

    // layer 1
    k_gemm_in<<<(N_NODES + 255) / 256, 256, 0, stream>>>(x, Wf + WF_W1, dinv, hs, flag);
    k_agg<<<(N_NODES / 2 + 3) / 4, 256, 0, stream>>>(hs, rowptr, csrsrc, dinv, Wf + WF_B1, h);

    // layer 2
    k_gemm64<<<(N_NODES + 255) / 256, 256, 0, stream>>>(h, Wf + WF_W2, dinv, hs);
    k_agg<<<(N_NODES / 2 + 3) / 4, 256, 0, stream>>>(hs, rowptr, csrsrc, dinv, Wf + WF_B2, h);

    // edge MLP: P1 -> hs, P2 in place on h; then CSR-ordered edge pass
    k_pair<<<(N_NODES + 255) / 256, 256, 0, stream>>>(h, Wf + WF_L1W, hs);
    k_edge<<<(N_EDGES + 255) / 256, 256, 0, stream>>>(csrsrc, csreid, csrcol,
                                                      hs, h, Wf, flag, d_out);
}

// Round 11
// 619.115 us; speedup vs baseline: 1.0426x; 1.0426x over previous
//
#include <hip/hip_runtime.h>
#include <hip/hip_bf16.h>

#define N_NODES 100000
#define N_EDGES 1600000
#define F_IN 128
#define HID 64
#define SCAN_NB 98  // ceil(100000/1024)

typedef __attribute__((ext_vector_type(8))) short short8;

__device__ __forceinline__ float bfbits2f(unsigned short u) {
    union { unsigned int i; float f; } v;
    v.i = ((unsigned int)u) << 16;
    return v.f;
}
__device__ __forceinline__ unsigned short f2bfbits(float f) {
    union { float f; unsigned int i; } v;
    v.f = f;
    unsigned int r = v.i + 0x7FFFu + ((v.i >> 16) & 1u);  // RNE
    return (unsigned short)(r >> 16);
}
__device__ __forceinline__ unsigned int pack2bf(float a, float b) {
    return ((unsigned int)f2bfbits(b) << 16) | (unsigned int)f2bfbits(a);
}
__device__ __forceinline__ float lo_bf(unsigned int w) { return bfbits2f((unsigned short)(w & 0xFFFF)); }
__device__ __forceinline__ float hi_bf(unsigned int w) { return bfbits2f((unsigned short)(w >> 16)); }

// ---- detect flags AND zero deg (memset folded in); block 0 does flag logic ----
// flag[0] = edge_index is int64; flag[1] = model dtype is bf16
__global__ void k_detect(const int* __restrict__ ei, const unsigned int* __restrict__ x32,
                         int* __restrict__ flag, int* __restrict__ deg) {
    int gid = blockIdx.x * 1024 + threadIdx.x;
    if (gid < N_NODES) deg[gid] = 0;
    if (blockIdx.x != 0) return;
    __shared__ int s_odd, s_cnt;
    if (threadIdx.x == 0) { s_odd = 0; s_cnt = 0; }
    __syncthreads();
    int t = threadIdx.x;  // 1024 threads
    if (ei[2 * t + 1] != 0) atomicOr(&s_odd, 1);
    if (t < 256) {
        unsigned int u = x32[t];
        unsigned int e = (u >> 7) & 0xFF;
        if (e >= 0x68 && e <= 0x97) atomicAdd(&s_cnt, 1);
    }
    __syncthreads();
    if (t == 0) {
        flag[0] = (s_odd == 0) ? 1 : 0;
        flag[1] = (s_cnt >= 160) ? 1 : 0;
    }
}

__device__ __forceinline__ int clampN(int v) {
    v = v < 0 ? 0 : v;
    return v > (N_NODES - 1) ? (N_NODES - 1) : v;
}
__device__ __forceinline__ int load_row(const int* __restrict__ ei, int f, int e) {
    return clampN(f ? ei[2 * e] : ei[e]);
}
__device__ __forceinline__ int load_col(const int* __restrict__ ei, int f, int e) {
    return clampN(f ? ei[2 * (N_EDGES + e)] : ei[N_EDGES + e]);
}

// ---- fp32 weight scratch layout (floats) ----
#define WF_W1   0
#define WF_W2   8192
#define WF_L1W  12288
#define WF_B1   20480
#define WF_B2   20544
#define WF_L1B  20608
#define WF_L2W  20672
#define WF_L2B  20800
#define WF_TOT  20802

__global__ void k_prep(const void* W1, const void* W2, const void* L1W,
                       const void* b1, const void* b2, const void* L1b,
                       const void* L2W, const void* L2b,
                       const int* __restrict__ flag, float* __restrict__ Wf) {
    int idx = blockIdx.x * blockDim.x + threadIdx.x;
    if (idx >= WF_TOT) return;
    int bf = flag[1];
    const void* src; int k;
    if      (idx < WF_W2)  { src = W1;  k = idx; }
    else if (idx < WF_L1W) { src = W2;  k = idx - WF_W2; }
    else if (idx < WF_B1)  { src = L1W; k = idx - WF_L1W; }
    else if (idx < WF_B2)  { src = b1;  k = idx - WF_B1; }
    else if (idx < WF_L1B) { src = b2;  k = idx - WF_B2; }
    else if (idx < WF_L2W) { src = L1b; k = idx - WF_L1B; }
    else if (idx < WF_L2B) { src = L2W; k = idx - WF_L2W; }
    else                   { src = L2b; k = idx - WF_L2B; }
    Wf[idx] = bf ? bfbits2f(((const unsigned short*)src)[k]) : ((const float*)src)[k];
}

__global__ void k_deg(const int* __restrict__ ei, const int* __restrict__ flag,
                      int* __restrict__ deg) {
    int e = blockIdx.x * blockDim.x + threadIdx.x;
    if (e >= N_EDGES) return;
    atomicAdd(&deg[load_col(ei, flag[0], e)], 1);
}

// ---- CSR build: scan1 also computes dinv and zeroes deg (cursor reuse) ----
__global__ void k_scan1(int* __restrict__ deg, int* __restrict__ rowptr,
                        int* __restrict__ bsum, float* __restrict__ dinv) {
    __shared__ int s[1024];
    int t = threadIdx.x, b = blockIdx.x;
    int i = b * 1024 + t;
    int v = (i < N_NODES) ? deg[i] : 0;
    if (i < N_NODES) {
        dinv[i] = rsqrtf((float)(v + 1));
        deg[i] = 0;  // becomes the fill cursor
    }
    s[t] = v; __syncthreads();
    for (int off = 1; off < 1024; off <<= 1) {
        int add = (t >= off) ? s[t - off] : 0;
        __syncthreads();
        s[t] += add;
        __syncthreads();
    }
    if (i < N_NODES) rowptr[i] = s[t] - v;
    if (t == 1023) bsum[b] = s[t];
}

__global__ void k_scan2(const int* __restrict__ bsum, int* __restrict__ boff,
                        int* __restrict__ rowptr) {
    __shared__ int s[128];
    int t = threadIdx.x;
    int v = (t < SCAN_NB) ? bsum[t] : 0;
    s[t] = v; __syncthreads();
    for (int off = 1; off < 128; off <<= 1) {
        int add = (t >= off) ? s[t - off] : 0;
        __syncthreads();
        s[t] += add;
        __syncthreads();
    }
    if (t < SCAN_NB) boff[t] = s[t] - v;
    if (t == 0) rowptr[N_NODES] = N_EDGES;
}

__global__ void k_scan3(int* __restrict__ rowptr, const int* __restrict__ boff) {
    int t = threadIdx.x, b = blockIdx.x;
    int i = b * 1024 + t;
    if (i < N_NODES) rowptr[i] += boff[b];
}

// ---- fill: three independent 4-B scattered stores, 1 edge/thread ----
// Measured optimum (r5/r9: 94 µs). TLP-bound: 2 e/t (r10, 117) and int2 (r7, 112) both lose.
__global__ void k_fill(const int* __restrict__ ei, const int* __restrict__ flag,
                       const int* __restrict__ rowptr, int* __restrict__ cursor,
                       int* __restrict__ csr_src, int* __restrict__ csr_col,
                       int* __restrict__ csr_eid) {
    int e = blockIdx.x * blockDim.x + threadIdx.x;
    if (e >= N_EDGES) return;
    int f = flag[0];
    int r = load_row(ei, f, e), c = load_col(ei, f, e);
    int pos = atomicAdd(&cursor[c], 1);
    int slot = rowptr[c] + pos;
    csr_src[slot] = r;
    csr_col[slot] = c;
    csr_eid[slot] = e;
}

// ===== node tables: packed bf16 rows, 32 u32 (=64 ch) per node =====
// All GEMMs: thread-per-node, 64 fp32 accs, WAVE-UNIFORM weight rows (s_load path).
// NEVER role-fuse these with latency-bound kernels (round-8: VGPR spill at 56).

__device__ __forceinline__ void st_row_bf(unsigned int* tab, int node, const float* acc, float s) {
    unsigned int* op = tab + (size_t)node * 32;
#pragma unroll
    for (int j = 0; j < 64; j += 2) op[j >> 1] = pack2bf(acc[j] * s, acc[j + 1] * s);
}

__device__ __forceinline__ void fma8(const float* xv, const float* __restrict__ Wf,
                                     int k0, float* acc) {
#pragma unroll
    for (int t = 0; t < 8; t++) {
        const float* wr = Wf + (k0 + t) * 64;
#pragma unroll
        for (int j = 0; j < 64; j++) acc[j] = fmaf(xv[t], wr[j], acc[j]);
    }
}

// ---- layer-1 GEMM: x [N,128] (bf16 or fp32) @ Wf[128,64] -> hs (bf16 rows) ----
__global__ void __launch_bounds__(256) k_gemm_in(const void* __restrict__ x,
                                                 const float* __restrict__ Wf,
                                                 const float* __restrict__ dinv,
                                                 unsigned int* __restrict__ hs,
                                                 const int* __restrict__ flag) {
    int i = blockIdx.x * blockDim.x + threadIdx.x;
    if (i >= N_NODES) return;
    int bf = flag[1];
    float acc[64];
#pragma unroll
    for (int j = 0; j < 64; j++) acc[j] = 0.f;
    if (bf) {
        const unsigned short* xp = (const unsigned short*)x + (size_t)i * F_IN;
#pragma unroll 2
        for (int k0 = 0; k0 < F_IN; k0 += 8) {
            short8 raw = *(const short8*)(xp + k0);
            float xv[8];
#pragma unroll
            for (int t = 0; t < 8; t++) xv[t] = bfbits2f((unsigned short)raw[t]);
            fma8(xv, Wf, k0, acc);
        }
    } else {
        const float* xp = (const float*)x + (size_t)i * F_IN;
#pragma unroll 2
        for (int k0 = 0; k0 < F_IN; k0 += 8) {
            float4 a = *(const float4*)(xp + k0);
            float4 b = *(const float4*)(xp + k0 + 4);
            float xv[8] = {a.x, a.y, a.z, a.w, b.x, b.y, b.z, b.w};
            fma8(xv, Wf, k0, acc);
        }
    }
    st_row_bf(hs, i, acc, dinv[i]);
}

// ---- generic K=64 GEMM: in (bf16 rows) @ W[64][64] -> out (bf16 rows); scale opt ----
__global__ void __launch_bounds__(256) k_gemm64(const unsigned int* __restrict__ in,
                                                const float* __restrict__ W,
                                                const float* __restrict__ scale,
                                                unsigned int* __restrict__ out) {
    int i = blockIdx.x * blockDim.x + threadIdx.x;
    if (i >= N_NODES) return;
    float acc[64];
#pragma unroll
    for (int j = 0; j < 64; j++) acc[j] = 0.f;
    const unsigned short* hp = (const unsigned short*)(in + (size_t)i * 32);
#pragma unroll 2
    for (int k0 = 0; k0 < 64; k0 += 8) {
        short8 raw = *(const short8*)(hp + k0);
        float xv[8];
#pragma unroll
        for (int t = 0; t < 8; t++) xv[t] = bfbits2f((unsigned short)raw[t]);
        fma8(xv, W, k0, acc);
    }
    float s = scale ? scale[i] : 1.f;
    st_row_bf(out, i, acc, s);
}

// ---- P1 then P2 sequentially per thread (64 accs live at a time -> no spill) ----
__global__ void __launch_bounds__(256) k_pair(unsigned int* __restrict__ h,
                                              const float* __restrict__ W,  // L1W [128][64]
                                              unsigned int* __restrict__ P1) {
    int i = blockIdx.x * blockDim.x + threadIdx.x;
    if (i >= N_NODES) return;
    const unsigned short* hp = (const unsigned short*)(h + (size_t)i * 32);
    float acc[64];
    // P1 = h @ W[0:64]
#pragma unroll
    for (int j = 0; j < 64; j++) acc[j] = 0.f;
#pragma unroll 2
    for (int k0 = 0; k0 < 64; k0 += 8) {
        short8 raw = *(const short8*)(hp + k0);
        float xv[8];
#pragma unroll
        for (int t = 0; t < 8; t++) xv[t] = bfbits2f((unsigned short)raw[t]);
        fma8(xv, W, k0, acc);
    }
    st_row_bf(P1, i, acc, 1.f);
    // P2 = h @ W[64:128], in place on h (row re-read is L1-hot)
#pragma unroll
    for (int j = 0; j < 64; j++) acc[j] = 0.f;
#pragma unroll 2
    for (int k0 = 0; k0 < 64; k0 += 8) {
        short8 raw = *(const short8*)(hp + k0);
        float xv[8];
#pragma unroll
        for (int t = 0; t < 8; t++) xv[t] = bfbits2f((unsigned short)raw[t]);
        fma8(xv, W + 64 * 64, k0, acc);
    }
    st_row_bf(h, i, acc, 1.f);
}

// ---- fused aggregate: wave = 2 nodes; 32 lanes/node; lane w handles ch 2w,2w+1 ----
// Neighbor loop unrolled x4: 4 outstanding gathers to hide L2/HBM load latency.
__global__ void __launch_bounds__(256) k_agg(const unsigned int* __restrict__ hs,
                                             const int* __restrict__ rowptr,
                                             const int* __restrict__ csr_src,
                                             const float* __restrict__ dinv,
                                             const float* __restrict__ bias,
                                             unsigned int* __restrict__ h) {
    int waves_per_blk = blockDim.x >> 6;
    int wid = blockIdx.x * waves_per_blk + (threadIdx.x >> 6);
    int lane = threadIdx.x & 63;
    int half = lane >> 5;
    int w = lane & 31;
    int node = wid * 2 + half;
    if (node >= N_NODES) return;
    unsigned int sw = hs[(size_t)node * 32 + w];
    float a0 = lo_bf(sw), a1 = hi_bf(sw);
    int k = rowptr[node], k1 = rowptr[node + 1];
    for (; k + 3 < k1; k += 4) {
        int s0 = csr_src[k], s1 = csr_src[k + 1], s2 = csr_src[k + 2], s3 = csr_src[k + 3];
        unsigned int w0 = hs[(size_t)s0 * 32 + w];
        unsigned int w1 = hs[(size_t)s1 * 32 + w];
        unsigned int w2 = hs[(size_t)s2 * 32 + w];
        unsigned int w3 = hs[(size_t)s3 * 32 + w];
        a0 += (lo_bf(w0) + lo_bf(w1)) + (lo_bf(w2) + lo_bf(w3));
        a1 += (hi_bf(w0) + hi_bf(w1)) + (hi_bf(w2) + hi_bf(w3));
    }
    for (; k < k1; k++) {
        unsigned int w0 = hs[(size_t)csr_src[k] * 32 + w];
        a0 += lo_bf(w0);
        a1 += hi_bf(w0);
    }
    float di = dinv[node];
    float v0 = fmaxf(fmaf(a0, di, bias[2 * w]), 0.f);
    float v1 = fmaxf(fmaf(a1, di, bias[2 * w + 1]), 0.f);
    h[(size_t)node * 32 + w] = pack2bf(v0, v1);
}

// ---- edge MLP in CSR order ----
__global__ void k_edge(const int* __restrict__ csr_src, const int* __restrict__ csr_eid,
                       const int* __restrict__ csr_col,
                       const unsigned int* __restrict__ P1, const unsigned int* __restrict__ P2,
                       const float* __restrict__ Wf, const int* __restrict__ flag,
                       void* __restrict__ out) {
    int s = blockIdx.x * blockDim.x + threadIdx.x;
    if (s >= N_EDGES) return;
    int r = csr_src[s], eid = csr_eid[s], c = csr_col[s];
    const float* l1b = Wf + WF_L1B;
    const float* l2w = Wf + WF_L2W;
    const float* l2b = Wf + WF_L2B;
    const uint4* p1 = (const uint4*)(P1 + (size_t)r * 32);
    const uint4* p2 = (const uint4*)(P2 + (size_t)c * 32);
    float s0 = 0.f, s1 = 0.f;
#pragma unroll
    for (int q = 0; q < 8; q++) {
        uint4 ua = p1[q];
        uint4 ub = p2[q];
        unsigned int wa[4] = {ua.x, ua.y, ua.z, ua.w};
        unsigned int wb[4] = {ub.x, ub.y, ub.z, ub.w};
#pragma unroll
        for (int t = 0; t < 4; t++) {
            int j = q * 8 + t * 2;
            float z;
            z = fmaxf(lo_bf(wa[t]) + lo_bf(wb[t]) + l1b[j + 0], 0.f);
            s0 = fmaf(z, l2w[(j + 0) * 2], s0); s1 = fmaf(z, l2w[(j + 0) * 2 + 1], s1);
            z = fmaxf(hi_bf(wa[t]) + hi_bf(wb[t]) + l1b[j + 1], 0.f);
            s0 = fmaf(z, l2w[(j + 1) * 2], s0); s1 = fmaf(z, l2w[(j + 1) * 2 + 1], s1);
        }
    }
    float z0 = s0 + l2b[0];
    float z1 = s1 + l2b[1];
    float m = fmaxf(z0, z1);
    float lse = m + __logf(__expf(z0 - m) + __expf(z1 - m));
    if (flag[1]) {
        ((unsigned int*)out)[eid] = pack2bf(z0 - lse, z1 - lse);
    } else {
        float2 v; v.x = z0 - lse; v.y = z1 - lse;
        ((float2*)out)[eid] = v;
    }
}

extern "C" void kernel_launch(void* const* d_in, const int* in_sizes, int n_in,
                              void* d_out, int out_size, void* d_ws, size_t ws_size,
                              hipStream_t stream) {
    const void* x   = d_in[0];
    const int*  ei  = (const int*)d_in[1];

    char* ws = (char*)d_ws;
    constexpr size_t KB = 1024;

    // peak use 46100 KB (same as rounds 6-10, which passed)
    int*   deg    = (int*)(ws);                    // 400 KB (reused as cursor)
    float* dinv   = (float*)(ws + 400 * KB);       // 400 KB
    int*   rowptr = (int*)(ws + 800 * KB);         // 400 KB + 4
    int*   flag   = (int*)(ws + 1204 * KB);        // 8 B
    int*   bsum   = (int*)(ws + 1208 * KB);        // 392 B
    int*   boff   = (int*)(ws + 1212 * KB);        // 392 B
    float* Wf     = (float*)(ws + 1216 * KB);      // 83.2 KB -> ends 1299.2 KB
    int*   csrsrc = (int*)(ws + 1300 * KB);        // 6400 KB -> ends 7700
    int*   csreid = (int*)(ws + 7700 * KB);        // 6400 KB -> ends 14100
    int*   csrcol = (int*)(ws + 14100 * KB);       // 6400 KB -> ends 20500
    unsigned int* hs = (unsigned int*)(ws + 20500 * KB);  // 12800 KB (later P1)
    unsigned int* h  = (unsigned int*)(ws + 33300 * KB);  // 12800 KB (later P2)

    // detect + deg-zero fused (neutral r10, saves a dispatch)
    k_detect<<<SCAN_NB, 1024, 0, stream>>>(ei, (const unsigned int*)x, flag, deg);
    k_prep<<<(WF_TOT + 255) / 256, 256, 0, stream>>>(d_in[2], d_in[4], d_in[6], d_in[3],
                                                     d_in[5], d_in[7], d_in[8], d_in[9],
                                                     flag, Wf);
    k_deg<<<(N_EDGES + 255) / 256, 256, 0, stream>>>(ei, flag, deg);

    // CSR build (scan1 also emits dinv and zeroes deg -> cursor)
    k_scan1<<<SCAN_NB, 1024, 0, stream>>>(deg, rowptr, bsum, dinv);
    k_scan2<<<1, 128, 0, stream>>>(bsum, boff, rowptr);
    k_scan3<<<SCAN_NB, 1024, 0, stream>>>(rowptr, boff);
    k_fill<<<(N_EDGES + 255) / 256, 256, 0, stream>>>(ei, flag, rowptr, deg,
                                                      csrsrc, csrcol, csreid);

    // layer 1
    k_gemm_in<<<(N_NODES + 255) / 256, 256, 0, stream>>>(x, Wf + WF_W1, dinv, hs, flag);
    k_agg<<<(N_NODES / 2 + 3) / 4, 256, 0, stream>>>(hs, rowptr, csrsrc, dinv, Wf + WF_B1, h);

    // layer 2
    k_gemm64<<<(N_NODES + 255) / 256, 256, 0, stream>>>(h, Wf + WF_W2, dinv, hs);
    k_agg<<<(N_NODES / 2 + 3) / 4, 256, 0, stream>>>(hs, rowptr, csrsrc, dinv, Wf + WF_B2, h);

    // edge MLP: P1 -> hs, P2 in place on h; then CSR-ordered edge pass
    k_pair<<<(N_NODES + 255) / 256, 256, 0, stream>>>(h, Wf + WF_L1W, hs);
    k_edge<<<(N_EDGES + 255) / 256, 256, 0, stream>>>(csrsrc, csreid, csrcol,
                                                      hs, h, Wf, flag, d_out);
}

// Round 12
// 496.850 us; speedup vs baseline: 1.2991x; 1.2461x over previous
//
#include <hip/hip_runtime.h>
#include <hip/hip_bf16.h>

#define N_NODES 100000
#define N_EDGES 1600000
#define F_IN 128
#define HID 64
#define SCAN_NB 98  // ceil(100000/1024)

typedef __attribute__((ext_vector_type(8))) short short8;

__device__ __forceinline__ float bfbits2f(unsigned short u) {
    union { unsigned int i; float f; } v;
    v.i = ((unsigned int)u) << 16;
    return v.f;
}
__device__ __forceinline__ unsigned short f2bfbits(float f) {
    union { float f; unsigned int i; } v;
    v.f = f;
    unsigned int r = v.i + 0x7FFFu + ((v.i >> 16) & 1u);  // RNE
    return (unsigned short)(r >> 16);
}
__device__ __forceinline__ unsigned int pack2bf(float a, float b) {
    return ((unsigned int)f2bfbits(b) << 16) | (unsigned int)f2bfbits(a);
}
__device__ __forceinline__ float lo_bf(unsigned int w) { return bfbits2f((unsigned short)(w & 0xFFFF)); }
__device__ __forceinline__ float hi_bf(unsigned int w) { return bfbits2f((unsigned short)(w >> 16)); }

// ---- detect flags AND zero deg; block 0 does flag logic ----
__global__ void k_detect(const int* __restrict__ ei, const unsigned int* __restrict__ x32,
                         int* __restrict__ flag, int* __restrict__ deg) {
    int gid = blockIdx.x * 1024 + threadIdx.x;
    if (gid < N_NODES) deg[gid] = 0;
    if (blockIdx.x != 0) return;
    __shared__ int s_odd, s_cnt;
    if (threadIdx.x == 0) { s_odd = 0; s_cnt = 0; }
    __syncthreads();
    int t = threadIdx.x;  // 1024 threads
    if (ei[2 * t + 1] != 0) atomicOr(&s_odd, 1);
    if (t < 256) {
        unsigned int u = x32[t];
        unsigned int e = (u >> 7) & 0xFF;
        if (e >= 0x68 && e <= 0x97) atomicAdd(&s_cnt, 1);
    }
    __syncthreads();
    if (t == 0) {
        flag[0] = (s_odd == 0) ? 1 : 0;
        flag[1] = (s_cnt >= 160) ? 1 : 0;
    }
}

__device__ __forceinline__ int clampN(int v) {
    v = v < 0 ? 0 : v;
    return v > (N_NODES - 1) ? (N_NODES - 1) : v;
}
__device__ __forceinline__ int load_row(const int* __restrict__ ei, int f, int e) {
    return clampN(f ? ei[2 * e] : ei[e]);
}
__device__ __forceinline__ int load_col(const int* __restrict__ ei, int f, int e) {
    return clampN(f ? ei[2 * (N_EDGES + e)] : ei[N_EDGES + e]);
}

// ---- fp32 weight scratch layout (floats) ----
#define WF_W1   0
#define WF_W2   8192
#define WF_L1W  12288
#define WF_B1   20480
#define WF_B2   20544
#define WF_L1B  20608
#define WF_L2W  20672
#define WF_L2B  20800
#define WF_TOT  20802

__global__ void k_prep(const void* W1, const void* W2, const void* L1W,
                       const void* b1, const void* b2, const void* L1b,
                       const void* L2W, const void* L2b,
                       const int* __restrict__ flag, float* __restrict__ Wf) {
    int idx = blockIdx.x * blockDim.x + threadIdx.x;
    if (idx >= WF_TOT) return;
    int bf = flag[1];
    const void* src; int k;
    if      (idx < WF_W2)  { src = W1;  k = idx; }
    else if (idx < WF_L1W) { src = W2;  k = idx - WF_W2; }
    else if (idx < WF_B1)  { src = L1W; k = idx - WF_L1W; }
    else if (idx < WF_B2)  { src = b1;  k = idx - WF_B1; }
    else if (idx < WF_L1B) { src = b2;  k = idx - WF_B2; }
    else if (idx < WF_L2W) { src = L1b; k = idx - WF_L1B; }
    else if (idx < WF_L2B) { src = L2W; k = idx - WF_L2W; }
    else                   { src = L2b; k = idx - WF_L2B; }
    Wf[idx] = bf ? bfbits2f(((const unsigned short*)src)[k]) : ((const float*)src)[k];
}

__global__ void k_deg(const int* __restrict__ ei, const int* __restrict__ flag,
                      int* __restrict__ deg) {
    int e = blockIdx.x * blockDim.x + threadIdx.x;
    if (e >= N_EDGES) return;
    atomicAdd(&deg[load_col(ei, flag[0], e)], 1);
}

// ---- CSR build: scan1 also computes dinv and zeroes deg (cursor reuse) ----
__global__ void k_scan1(int* __restrict__ deg, int* __restrict__ rowptr,
                        int* __restrict__ bsum, float* __restrict__ dinv) {
    __shared__ int s[1024];
    int t = threadIdx.x, b = blockIdx.x;
    int i = b * 1024 + t;
    int v = (i < N_NODES) ? deg[i] : 0;
    if (i < N_NODES) {
        dinv[i] = rsqrtf((float)(v + 1));
        deg[i] = 0;  // becomes the fill cursor
    }
    s[t] = v; __syncthreads();
    for (int off = 1; off < 1024; off <<= 1) {
        int add = (t >= off) ? s[t - off] : 0;
        __syncthreads();
        s[t] += add;
        __syncthreads();
    }
    if (i < N_NODES) rowptr[i] = s[t] - v;
    if (t == 1023) bsum[b] = s[t];
}

__global__ void k_scan2(const int* __restrict__ bsum, int* __restrict__ boff,
                        int* __restrict__ rowptr) {
    __shared__ int s[128];
    int t = threadIdx.x;
    int v = (t < SCAN_NB) ? bsum[t] : 0;
    s[t] = v; __syncthreads();
    for (int off = 1; off < 128; off <<= 1) {
        int add = (t >= off) ? s[t - off] : 0;
        __syncthreads();
        s[t] += add;
        __syncthreads();
    }
    if (t < SCAN_NB) boff[t] = s[t] - v;
    if (t == 0) rowptr[N_NODES] = N_EDGES;
}

__global__ void k_scan3(int* __restrict__ rowptr, const int* __restrict__ boff) {
    int t = threadIdx.x, b = blockIdx.x;
    int i = b * 1024 + t;
    if (i < N_NODES) rowptr[i] += boff[b];
}

// ---- fill: three independent 4-B scattered stores, 1 edge/thread (measured optimum) ----
__global__ void k_fill(const int* __restrict__ ei, const int* __restrict__ flag,
                       const int* __restrict__ rowptr, int* __restrict__ cursor,
                       int* __restrict__ csr_src, int* __restrict__ csr_col,
                       int* __restrict__ csr_eid) {
    int e = blockIdx.x * blockDim.x + threadIdx.x;
    if (e >= N_EDGES) return;
    int f = flag[0];
    int r = load_row(ei, f, e), c = load_col(ei, f, e);
    int pos = atomicAdd(&cursor[c], 1);
    int slot = rowptr[c] + pos;
    csr_src[slot] = r;
    csr_col[slot] = c;
    csr_eid[slot] = e;
}

// ===== node tables: packed bf16 rows, 32 u32 (=64 ch) per node =====
// Wave-split GEMMs: each WAVE owns a (node-group, col-half); the half index is
// forced into an SGPR via readfirstlane so weight reads stay on the s_load path
// (round-6's lane-divergent coloff destroyed this; round-11's acc[64] spilled at
// the VGPR=56 cap). acc[32]/thread -> no spill.

__device__ __forceinline__ void fma8_32(const float* xv, const float* __restrict__ W,
                                        int k0, int coloff, float* acc) {
#pragma unroll
    for (int t = 0; t < 8; t++) {
        const float* wr = W + (k0 + t) * 64 + coloff;
#pragma unroll
        for (int j = 0; j < 32; j++) acc[j] = fmaf(xv[t], wr[j], acc[j]);
    }
}

// ---- layer-1 GEMM (wave-split): x [N,128] @ Wf[128,64] -> hs bf16; scale=dinv ----
__global__ void __launch_bounds__(256) k_gemm_in_ws(const void* __restrict__ x,
                                                    const float* __restrict__ Wf,
                                                    const float* __restrict__ dinv,
                                                    unsigned int* __restrict__ hs,
                                                    const int* __restrict__ flag) {
    int wv = __builtin_amdgcn_readfirstlane(threadIdx.x >> 6);  // 0..3, scalar
    int wid = blockIdx.x * 4 + wv;
    int group = wid >> 1;
    int half = wid & 1;          // scalar: col-half
    int lane = threadIdx.x & 63;
    int node = group * 64 + lane;
    if (node >= N_NODES) return;
    int bf = flag[1];
    int coloff = half * 32;
    float acc[32];
#pragma unroll
    for (int j = 0; j < 32; j++) acc[j] = 0.f;
    if (bf) {
        const unsigned short* xp = (const unsigned short*)x + (size_t)node * F_IN;
#pragma unroll 2
        for (int k0 = 0; k0 < F_IN; k0 += 8) {
            short8 raw = *(const short8*)(xp + k0);
            float xv[8];
#pragma unroll
            for (int t = 0; t < 8; t++) xv[t] = bfbits2f((unsigned short)raw[t]);
            fma8_32(xv, Wf, k0, coloff, acc);
        }
    } else {
        const float* xp = (const float*)x + (size_t)node * F_IN;
#pragma unroll 2
        for (int k0 = 0; k0 < F_IN; k0 += 8) {
            float4 a = *(const float4*)(xp + k0);
            float4 b = *(const float4*)(xp + k0 + 4);
            float xv[8] = {a.x, a.y, a.z, a.w, b.x, b.y, b.z, b.w};
            fma8_32(xv, Wf, k0, coloff, acc);
        }
    }
    float s = dinv[node];
    unsigned int* op = hs + (size_t)node * 32 + half * 16;
#pragma unroll
    for (int j = 0; j < 32; j += 2) op[j >> 1] = pack2bf(acc[j] * s, acc[j + 1] * s);
}

// ---- layer-2 GEMM (wave-split): in bf16 [N,64] @ W[64][64] -> out bf16; scale=dinv ----
__global__ void __launch_bounds__(256) k_gemm64_ws(const unsigned int* __restrict__ in,
                                                   const float* __restrict__ W,
                                                   const float* __restrict__ dinv,
                                                   unsigned int* __restrict__ out) {
    int wv = __builtin_amdgcn_readfirstlane(threadIdx.x >> 6);
    int wid = blockIdx.x * 4 + wv;
    int group = wid >> 1;
    int half = wid & 1;
    int lane = threadIdx.x & 63;
    int node = group * 64 + lane;
    if (node >= N_NODES) return;
    int coloff = half * 32;
    float acc[32];
#pragma unroll
    for (int j = 0; j < 32; j++) acc[j] = 0.f;
    const unsigned short* hp = (const unsigned short*)(in + (size_t)node * 32);
#pragma unroll 2
    for (int k0 = 0; k0 < 64; k0 += 8) {
        short8 raw = *(const short8*)(hp + k0);
        float xv[8];
#pragma unroll
        for (int t = 0; t < 8; t++) xv[t] = bfbits2f((unsigned short)raw[t]);
        fma8_32(xv, W, k0, coloff, acc);
    }
    float s = dinv[node];
    unsigned int* op = out + (size_t)node * 32 + half * 16;
#pragma unroll
    for (int j = 0; j < 32; j += 2) op[j >> 1] = pack2bf(acc[j] * s, acc[j + 1] * s);
}

// ---- edge-MLP projections (wave-split, 4 tasks): block = 64 nodes x 4 waves ----
// task 0,1 -> P1 cols 0-31 / 32-63 (L1W rows 0..63)  -> hs region
// task 2,3 -> P2 cols 0-31 / 32-63 (L1W rows 64..127) -> h in place
// __syncthreads between compute and store makes the in-place P2 write safe.
__global__ void __launch_bounds__(256) k_pair_ws(unsigned int* __restrict__ h,
                                                 const float* __restrict__ W,  // L1W [128][64]
                                                 unsigned int* __restrict__ P1) {
    int task = __builtin_amdgcn_readfirstlane(threadIdx.x >> 6);  // 0..3, scalar
    int lane = threadIdx.x & 63;
    int node = blockIdx.x * 64 + lane;
    bool valid = node < N_NODES;
    int coloff = (task & 1) * 32;
    const float* Wb = W + (task >> 1) * 64 * 64;  // k-row base: P1 rows 0.., P2 rows 64..
    float acc[32];
#pragma unroll
    for (int j = 0; j < 32; j++) acc[j] = 0.f;
    if (valid) {
        const unsigned short* hp = (const unsigned short*)(h + (size_t)node * 32);
#pragma unroll 2
        for (int k0 = 0; k0 < 64; k0 += 8) {
            short8 raw = *(const short8*)(hp + k0);
            float xv[8];
#pragma unroll
            for (int t = 0; t < 8; t++) xv[t] = bfbits2f((unsigned short)raw[t]);
            fma8_32(xv, Wb, k0, coloff, acc);
        }
    }
    __syncthreads();  // all reads of this block's 64 h-rows complete before P2 writes
    if (valid) {
        unsigned int* op = (task < 2 ? P1 : h) + (size_t)node * 32 + coloff / 2;
#pragma unroll
        for (int j = 0; j < 32; j += 2) op[j >> 1] = pack2bf(acc[j], acc[j + 1]);
    }
}

// ---- fused aggregate: wave = 2 nodes; 32 lanes/node; x4 unroll for gather ILP ----
__global__ void __launch_bounds__(256) k_agg(const unsigned int* __restrict__ hs,
                                             const int* __restrict__ rowptr,
                                             const int* __restrict__ csr_src,
                                             const float* __restrict__ dinv,
                                             const float* __restrict__ bias,
                                             unsigned int* __restrict__ h) {
    int waves_per_blk = blockDim.x >> 6;
    int wid = blockIdx.x * waves_per_blk + (threadIdx.x >> 6);
    int lane = threadIdx.x & 63;
    int half = lane >> 5;
    int w = lane & 31;
    int node = wid * 2 + half;
    if (node >= N_NODES) return;
    unsigned int sw = hs[(size_t)node * 32 + w];
    float a0 = lo_bf(sw), a1 = hi_bf(sw);
    int k = rowptr[node], k1 = rowptr[node + 1];
    for (; k + 3 < k1; k += 4) {
        int s0 = csr_src[k], s1 = csr_src[k + 1], s2 = csr_src[k + 2], s3 = csr_src[k + 3];
        unsigned int w0 = hs[(size_t)s0 * 32 + w];
        unsigned int w1 = hs[(size_t)s1 * 32 + w];
        unsigned int w2 = hs[(size_t)s2 * 32 + w];
        unsigned int w3 = hs[(size_t)s3 * 32 + w];
        a0 += (lo_bf(w0) + lo_bf(w1)) + (lo_bf(w2) + lo_bf(w3));
        a1 += (hi_bf(w0) + hi_bf(w1)) + (hi_bf(w2) + hi_bf(w3));
    }
    for (; k < k1; k++) {
        unsigned int w0 = hs[(size_t)csr_src[k] * 32 + w];
        a0 += lo_bf(w0);
        a1 += hi_bf(w0);
    }
    float di = dinv[node];
    float v0 = fmaxf(fmaf(a0, di, bias[2 * w]), 0.f);
    float v1 = fmaxf(fmaf(a1, di, bias[2 * w + 1]), 0.f);
    h[(size_t)node * 32 + w] = pack2bf(v0, v1);
}

// ---- edge MLP in CSR order ----
__global__ void k_edge(const int* __restrict__ csr_src, const int* __restrict__ csr_eid,
                       const int* __restrict__ csr_col,
                       const unsigned int* __restrict__ P1, const unsigned int* __restrict__ P2,
                       const float* __restrict__ Wf, const int* __restrict__ flag,
                       void* __restrict__ out) {
    int s = blockIdx.x * blockDim.x + threadIdx.x;
    if (s >= N_EDGES) return;
    int r = csr_src[s], eid = csr_eid[s], c = csr_col[s];
    const float* l1b = Wf + WF_L1B;
    const float* l2w = Wf + WF_L2W;
    const float* l2b = Wf + WF_L2B;
    const uint4* p1 = (const uint4*)(P1 + (size_t)r * 32);
    const uint4* p2 = (const uint4*)(P2 + (size_t)c * 32);
    float s0 = 0.f, s1 = 0.f;
#pragma unroll
    for (int q = 0; q < 8; q++) {
        uint4 ua = p1[q];
        uint4 ub = p2[q];
        unsigned int wa[4] = {ua.x, ua.y, ua.z, ua.w};
        unsigned int wb[4] = {ub.x, ub.y, ub.z, ub.w};
#pragma unroll
        for (int t = 0; t < 4; t++) {
            int j = q * 8 + t * 2;
            float z;
            z = fmaxf(lo_bf(wa[t]) + lo_bf(wb[t]) + l1b[j + 0], 0.f);
            s0 = fmaf(z, l2w[(j + 0) * 2], s0); s1 = fmaf(z, l2w[(j + 0) * 2 + 1], s1);
            z = fmaxf(hi_bf(wa[t]) + hi_bf(wb[t]) + l1b[j + 1], 0.f);
            s0 = fmaf(z, l2w[(j + 1) * 2], s0); s1 = fmaf(z, l2w[(j + 1) * 2 + 1], s1);
        }
    }
    float z0 = s0 + l2b[0];
    float z1 = s1 + l2b[1];
    float m = fmaxf(z0, z1);
    float lse = m + __logf(__expf(z0 - m) + __expf(z1 - m));
    if (flag[1]) {
        ((unsigned int*)out)[eid] = pack2bf(z0 - lse, z1 - lse);
    } else {
        float2 v; v.x = z0 - lse; v.y = z1 - lse;
        ((float2*)out)[eid] = v;
    }
}

extern "C" void kernel_launch(void* const* d_in, const int* in_sizes, int n_in,
                              void* d_out, int out_size, void* d_ws, size_t ws_size,
                              hipStream_t stream) {
    const void* x   = d_in[0];
    const int*  ei  = (const int*)d_in[1];

    char* ws = (char*)d_ws;
    constexpr size_t KB = 1024;

    // peak use 46100 KB (same as rounds 6-11, which passed)
    int*   deg    = (int*)(ws);                    // 400 KB (reused as cursor)
    float* dinv   = (float*)(ws + 400 * KB);       // 400 KB
    int*   rowptr = (int*)(ws + 800 * KB);         // 400 KB + 4
    int*   flag   = (int*)(ws + 1204 * KB);        // 8 B
    int*   bsum   = (int*)(ws + 1208 * KB);        // 392 B
    int*   boff   = (int*)(ws + 1212 * KB);        // 392 B
    float* Wf     = (float*)(ws + 1216 * KB);      // 83.2 KB -> ends 1299.2 KB
    int*   csrsrc = (int*)(ws + 1300 * KB);        // 6400 KB -> ends 7700
    int*   csreid = (int*)(ws + 7700 * KB);        // 6400 KB -> ends 14100
    int*   csrcol = (int*)(ws + 14100 * KB);       // 6400 KB -> ends 20500
    unsigned int* hs = (unsigned int*)(ws + 20500 * KB);  // 12800 KB (later P1)
    unsigned int* h  = (unsigned int*)(ws + 33300 * KB);  // 12800 KB (later P2)

    // detect + deg-zero fused
    k_detect<<<SCAN_NB, 1024, 0, stream>>>(ei, (const unsigned int*)x, flag, deg);
    k_prep<<<(WF_TOT + 255) / 256, 256, 0, stream>>>(d_in[2], d_in[4], d_in[6], d_in[3],
                                                     d_in[5], d_in[7], d_in[8], d_in[9],
                                                     flag, Wf);
    k_deg<<<(N_EDGES + 255) / 256, 256, 0, stream>>>(ei, flag, deg);

    // CSR build (scan1 also emits dinv and zeroes deg -> cursor)
    k_scan1<<<SCAN_NB, 1024, 0, stream>>>(deg, rowptr, bsum, dinv);
    k_scan2<<<1, 128, 0, stream>>>(bsum, boff, rowptr);
    k_scan3<<<SCAN_NB, 1024, 0, stream>>>(rowptr, boff);
    k_fill<<<(N_EDGES + 255) / 256, 256, 0, stream>>>(ei, flag, rowptr, deg,
                                                      csrsrc, csrcol, csreid);

    // wave-split grids: 2 waves/node-group(64) for gemms, 4 task-waves/64-node block for pair
    const int G = (N_NODES + 63) / 64;          // 1563 node groups
    const int gemm_blocks = (G * 2 + 3) / 4;    // 782

    // layer 1
    k_gemm_in_ws<<<gemm_blocks, 256, 0, stream>>>(x, Wf + WF_W1, dinv, hs, flag);
    k_agg<<<(N_NODES / 2 + 3) / 4, 256, 0, stream>>>(hs, rowptr, csrsrc, dinv, Wf + WF_B1, h);

    // layer 2
    k_gemm64_ws<<<gemm_blocks, 256, 0, stream>>>(h, Wf + WF_W2, dinv, hs);
    k_agg<<<(N_NODES / 2 + 3) / 4, 256, 0, stream>>>(hs, rowptr, csrsrc, dinv, Wf + WF_B2, h);

    // edge MLP: P1 -> hs, P2 in place on h (barrier-protected); CSR-ordered edge pass
    k_pair_ws<<<G, 256, 0, stream>>>(h, Wf + WF_L1W, hs);
    k_edge<<<(N_EDGES + 255) / 256, 256, 0, stream>>>(csrsrc, csreid, csrcol,
                                                      hs, h, Wf, flag, d_out);
}